// Round 9
// baseline (93.472 us; speedup 1.0000x reference)
//
#include <hip/hip_runtime.h>
#include <math.h>

// Problem constants (match reference)
static constexpr int   kC   = 1000;    // NUM_CLASSES
static constexpr int   kD   = 256;     // EMBED_DIM
static constexpr int   kCap = 1024;    // per-class index bin capacity
static constexpr float kMom = 0.995f;  // MOMENTUM
static constexpr float kEps = 1e-12f;  // F.normalize eps

typedef float f32x4 __attribute__((ext_vector_type(4)));

__device__ __forceinline__ f32x4 nt_load4(const float* p) {
    return __builtin_nontemporal_load((const f32x4*)p);
}

// ---- block-wide sum over 256 threads (4 waves of 64) ----
__device__ __forceinline__ float block_sum256(float v) {
    __shared__ float lds[4];
    #pragma unroll
    for (int off = 32; off > 0; off >>= 1) v += __shfl_down(v, off, 64);
    __syncthreads();                       // protect lds from prior call's reads
    if ((threadIdx.x & 63) == 0) lds[threadIdx.x >> 6] = v;
    __syncthreads();
    return lds[0] + lds[1] + lds[2] + lds[3];
}

// ---- pass 1: scatter row indices into fixed-capacity class bins ----
// 4 labels per thread via int4. Overflow (statistically never: counts ~
// Poisson(131), cap 1024) goes to a global (label,row) pair list.
__global__ void k_scatter(const int* __restrict__ labels, int n,
                          int* __restrict__ cnt, int* __restrict__ idx,
                          int* __restrict__ ovf /* [0]=count, then pairs */) {
    const int t = blockIdx.x * 256 + threadIdx.x;
    const int i0 = t * 4;
    if (i0 >= n) return;
    if (i0 + 3 < n) {
        const int4 l4 = ((const int4*)labels)[t];
        #pragma unroll
        for (int k = 0; k < 4; ++k) {
            const int lab = (&l4.x)[k];
            const int i = i0 + k;
            const int p = atomicAdd(&cnt[lab], 1);
            if (p < kCap) {
                idx[(size_t)lab * kCap + p] = i;
            } else {
                const int q = atomicAdd(&ovf[0], 1);
                ovf[1 + 2 * q] = lab; ovf[2 + 2 * q] = i;
            }
        }
    } else {
        for (int i = i0; i < n; ++i) {
            const int lab = labels[i];
            const int p = atomicAdd(&cnt[lab], 1);
            if (p < kCap) {
                idx[(size_t)lab * kCap + p] = i;
            } else {
                const int q = atomicAdd(&ovf[0], 1);
                ovf[1 + 2 * q] = lab; ovf[2 + 2 * q] = i;
            }
        }
    }
}

// ---- pass 2: per-class gather-sum + fused normalize/EMA epilogue ----
// one block (4 waves) per class; each row read = ONE float4/lane -> full 1 KB
// row in a single wave instruction. 8 rows in flight per wave.
__global__ void __launch_bounds__(256, 4)
k_reduce(const float* __restrict__ z, const float* __restrict__ protos,
         const int* __restrict__ initialized, const int* __restrict__ cnt,
         const int* __restrict__ idx, const int* __restrict__ ovf,
         float* __restrict__ out) {
    __shared__ int   sh_idx[kCap];
    __shared__ float sh_part[4][kD];

    const int c    = blockIdx.x;
    const int tid  = threadIdx.x;
    const int wave = tid >> 6;
    const int lane = tid & 63;

    const int cntc = cnt[c];
    const int m    = min(cntc, kCap);
    const int* __restrict__ cidx = idx + (size_t)c * kCap;

    // stage the whole class's index list once (<= 4 KB)
    for (int j = tid; j < m; j += 256) sh_idx[j] = cidx[j];
    __syncthreads();

    f32x4 acc0 = {0.f, 0.f, 0.f, 0.f};
    f32x4 acc1 = {0.f, 0.f, 0.f, 0.f};

    int r = wave;
    for (; r + 28 < m; r += 32) {           // 8 independent 1KB rows in flight
        const int i0 = sh_idx[r +  0]; const int i1 = sh_idx[r +  4];
        const int i2 = sh_idx[r +  8]; const int i3 = sh_idx[r + 12];
        const int i4 = sh_idx[r + 16]; const int i5 = sh_idx[r + 20];
        const int i6 = sh_idx[r + 24]; const int i7 = sh_idx[r + 28];
        const f32x4 a0 = nt_load4(z + (size_t)i0 * kD + lane * 4);
        const f32x4 a1 = nt_load4(z + (size_t)i1 * kD + lane * 4);
        const f32x4 a2 = nt_load4(z + (size_t)i2 * kD + lane * 4);
        const f32x4 a3 = nt_load4(z + (size_t)i3 * kD + lane * 4);
        const f32x4 a4 = nt_load4(z + (size_t)i4 * kD + lane * 4);
        const f32x4 a5 = nt_load4(z + (size_t)i5 * kD + lane * 4);
        const f32x4 a6 = nt_load4(z + (size_t)i6 * kD + lane * 4);
        const f32x4 a7 = nt_load4(z + (size_t)i7 * kD + lane * 4);
        acc0 += a0 + a1;
        acc1 += a2 + a3;
        acc0 += a4 + a5;
        acc1 += a6 + a7;
    }
    for (; r < m; r += 4) {
        acc0 += nt_load4(z + (size_t)sh_idx[r] * kD + lane * 4);
    }
    acc0 += acc1;

    ((f32x4*)&sh_part[wave][lane * 4])[0] = acc0;
    __syncthreads();

    const int d = tid;
    float sum = sh_part[0][d] + sh_part[1][d] + sh_part[2][d] + sh_part[3][d];

    // cold path: fold in overflow rows (ovf[0]==0 in practice)
    const int novf = ovf[0];
    if (novf > 0) {
        for (int j = 0; j < novf; ++j) {
            if (ovf[1 + 2 * j] == c) sum += z[(size_t)ovf[2 + 2 * j] * kD + d];
        }
    }

    const float mean   = sum / fmaxf((float)cntc, 1.0f);
    const float nrm    = sqrtf(block_sum256(mean * mean));
    const float mean_n = mean / fmaxf(nrm, kEps);

    const float p    = protos[c * kD + d];
    const float e    = kMom * p + (1.0f - kMom) * mean_n;
    const float nrm2 = sqrtf(block_sum256(e * e));
    const float ema  = e / fmaxf(nrm2, kEps);

    const float cand = (initialized[c] != 0) ? ema : mean_n;
    __builtin_nontemporal_store((cntc > 0) ? cand : p, &out[c * kD + d]);
}

// ================= fallback path (tiny ws): atomics into d_out ==============
__global__ void k_atomic_accum(const float* __restrict__ z,
                               const int* __restrict__ labels, int n,
                               float* __restrict__ sums, int* __restrict__ counts) {
    const int i = blockIdx.x;
    const int d = threadIdx.x;
    if (i >= n) return;
    const int lab = labels[i];
    atomicAdd(&sums[lab * kD + d], z[i * kD + d]);
    if (d == 0) atomicAdd(&counts[lab], 1);
}

__global__ void k_finalize_from_sums(const float* __restrict__ protos,
                                     const int* __restrict__ initialized,
                                     const int* __restrict__ counts,
                                     float* __restrict__ out) {
    const int c = blockIdx.x;
    const int d = threadIdx.x;
    const int cntc = counts[c];
    const float sum = out[c * kD + d];

    const float mean   = sum / fmaxf((float)cntc, 1.0f);
    const float nrm    = sqrtf(block_sum256(mean * mean));
    const float mean_n = mean / fmaxf(nrm, kEps);

    const float p    = protos[c * kD + d];
    const float e    = kMom * p + (1.0f - kMom) * mean_n;
    const float nrm2 = sqrtf(block_sum256(e * e));
    const float ema  = e / fmaxf(nrm2, kEps);

    const float cand = (initialized[c] != 0) ? ema : mean_n;
    out[c * kD + d] = (cntc > 0) ? cand : p;
}

extern "C" void kernel_launch(void* const* d_in, const int* in_sizes, int n_in,
                              void* d_out, int out_size, void* d_ws, size_t ws_size,
                              hipStream_t stream) {
    const float* z           = (const float*)d_in[0];
    const float* protos      = (const float*)d_in[1];
    const int*   initialized = (const int*)d_in[2];
    const int*   labels      = (const int*)d_in[3];
    const int n = in_sizes[3];          // N (labels count)
    float* out = (float*)d_out;

    // ws layout (4-byte units):
    //   [cnt: 1024][ovf: 8 + 2N (count + pairs)][idx: kC*kCap]
    int* ws  = (int*)d_ws;
    int* cnt = ws;                          // [1024]
    int* ovf = ws + 1024;                   // [8 + 2N]
    int* idx = ws + 1024 + 8 + 2 * n;       // [kC*kCap]
    const size_t need = (size_t)(1024 + 8 + 2 * (size_t)n + (size_t)kC * kCap)
                        * sizeof(int);

    if (ws_size >= need) {
        const int threads = (n + 3) / 4;
        const int blocks = (threads + 255) / 256;
        // ==== MEASUREMENT ROUND: run {memset, scatter} TWICE ====
        // Second pass re-zeroes cnt/ovf and rebuilds identical bins, so the
        // result is unchanged; dur delta vs the single-pass baseline (61.6us)
        // = cost of (memset + scatter).
        (void)hipMemsetAsync(ws, 0, (size_t)(1024 + 8) * sizeof(int), stream);
        k_scatter<<<blocks, 256, 0, stream>>>(labels, n, cnt, idx, ovf);
        (void)hipMemsetAsync(ws, 0, (size_t)(1024 + 8) * sizeof(int), stream);
        k_scatter<<<blocks, 256, 0, stream>>>(labels, n, cnt, idx, ovf);
        k_reduce <<<kC, kD, 0, stream>>>(z, protos, initialized, cnt, idx,
                                         ovf, out);
    } else {
        // fallback: accumulate sums directly in d_out with float atomics
        int* counts = ws;               // 4 KB
        (void)hipMemsetAsync(counts, 0, kC * sizeof(int), stream);
        (void)hipMemsetAsync(out, 0, (size_t)kC * kD * sizeof(float), stream);
        k_atomic_accum<<<n, kD, 0, stream>>>(z, labels, n, out, counts);
        k_finalize_from_sums<<<kC, kD, 0, stream>>>(protos, initialized, counts, out);
    }
}

// Round 10
// 43.416 us; speedup vs baseline: 2.1529x; 2.1529x over previous
//
#include <hip/hip_runtime.h>
#include <math.h>

// Problem constants (match reference)
static constexpr int   kC    = 1000;   // NUM_CLASSES
static constexpr int   kD    = 256;    // EMBED_DIM
static constexpr int   kCap  = 1024;   // per-class index bin capacity
static constexpr int   kCntS = 16;     // counter stride (ints) = 1 cache line
static constexpr float kMom  = 0.995f; // MOMENTUM
static constexpr float kEps  = 1e-12f; // F.normalize eps

typedef float f32x4 __attribute__((ext_vector_type(4)));

__device__ __forceinline__ f32x4 nt_load4(const float* p) {
    return __builtin_nontemporal_load((const f32x4*)p);
}

// ---- block-wide sum over 256 threads (4 waves of 64) ----
__device__ __forceinline__ float block_sum256(float v) {
    __shared__ float lds[4];
    #pragma unroll
    for (int off = 32; off > 0; off >>= 1) v += __shfl_down(v, off, 64);
    __syncthreads();                       // protect lds from prior call's reads
    if ((threadIdx.x & 63) == 0) lds[threadIdx.x >> 6] = v;
    __syncthreads();
    return lds[0] + lds[1] + lds[2] + lds[3];
}

// ---- pass 1: scatter row indices into fixed-capacity class bins ----
// Counters are PADDED to one per 64B cache line: line-level atomic
// serialization drops ~16x (round-9 measurement: scatter+memset ~= 32us).
__global__ void k_scatter(const int* __restrict__ labels, int n,
                          int* __restrict__ cnt /* stride kCntS */,
                          int* __restrict__ idx,
                          int* __restrict__ ovf /* [0]=count, then pairs */) {
    const int t = blockIdx.x * 256 + threadIdx.x;
    const int i0 = t * 4;
    if (i0 >= n) return;
    if (i0 + 3 < n) {
        const int4 l4 = ((const int4*)labels)[t];
        #pragma unroll
        for (int k = 0; k < 4; ++k) {
            const int lab = (&l4.x)[k];
            const int i = i0 + k;
            const int p = atomicAdd(&cnt[lab * kCntS], 1);
            if (p < kCap) {
                idx[(size_t)lab * kCap + p] = i;
            } else {  // statistically never (counts ~ Poisson(131), cap 1024)
                const int q = atomicAdd(&ovf[0], 1);
                ovf[1 + 2 * q] = lab; ovf[2 + 2 * q] = i;
            }
        }
    } else {
        for (int i = i0; i < n; ++i) {
            const int lab = labels[i];
            const int p = atomicAdd(&cnt[lab * kCntS], 1);
            if (p < kCap) {
                idx[(size_t)lab * kCap + p] = i;
            } else {
                const int q = atomicAdd(&ovf[0], 1);
                ovf[1 + 2 * q] = lab; ovf[2 + 2 * q] = i;
            }
        }
    }
}

// ---- pass 2: per-class gather-sum + fused normalize/EMA epilogue ----
// one block (4 waves) per class; each row read = ONE float4/lane -> full 1 KB
// row in a single wave instruction. 8 rows in flight per wave.
__global__ void __launch_bounds__(256, 4)
k_reduce(const float* __restrict__ z, const float* __restrict__ protos,
         const int* __restrict__ initialized, const int* __restrict__ cnt,
         const int* __restrict__ idx, const int* __restrict__ ovf,
         float* __restrict__ out) {
    __shared__ int   sh_idx[kCap];
    __shared__ float sh_part[4][kD];

    const int c    = blockIdx.x;
    const int tid  = threadIdx.x;
    const int wave = tid >> 6;
    const int lane = tid & 63;

    const int cntc = cnt[c * kCntS];
    const int m    = min(cntc, kCap);
    const int* __restrict__ cidx = idx + (size_t)c * kCap;

    // stage the whole class's index list once (<= 4 KB)
    for (int j = tid; j < m; j += 256) sh_idx[j] = cidx[j];
    __syncthreads();

    f32x4 acc0 = {0.f, 0.f, 0.f, 0.f};
    f32x4 acc1 = {0.f, 0.f, 0.f, 0.f};

    int r = wave;
    for (; r + 28 < m; r += 32) {           // 8 independent 1KB rows in flight
        const int i0 = sh_idx[r +  0]; const int i1 = sh_idx[r +  4];
        const int i2 = sh_idx[r +  8]; const int i3 = sh_idx[r + 12];
        const int i4 = sh_idx[r + 16]; const int i5 = sh_idx[r + 20];
        const int i6 = sh_idx[r + 24]; const int i7 = sh_idx[r + 28];
        const f32x4 a0 = nt_load4(z + (size_t)i0 * kD + lane * 4);
        const f32x4 a1 = nt_load4(z + (size_t)i1 * kD + lane * 4);
        const f32x4 a2 = nt_load4(z + (size_t)i2 * kD + lane * 4);
        const f32x4 a3 = nt_load4(z + (size_t)i3 * kD + lane * 4);
        const f32x4 a4 = nt_load4(z + (size_t)i4 * kD + lane * 4);
        const f32x4 a5 = nt_load4(z + (size_t)i5 * kD + lane * 4);
        const f32x4 a6 = nt_load4(z + (size_t)i6 * kD + lane * 4);
        const f32x4 a7 = nt_load4(z + (size_t)i7 * kD + lane * 4);
        acc0 += a0 + a1;
        acc1 += a2 + a3;
        acc0 += a4 + a5;
        acc1 += a6 + a7;
    }
    for (; r < m; r += 4) {
        acc0 += nt_load4(z + (size_t)sh_idx[r] * kD + lane * 4);
    }
    acc0 += acc1;

    ((f32x4*)&sh_part[wave][lane * 4])[0] = acc0;
    __syncthreads();

    const int d = tid;
    float sum = sh_part[0][d] + sh_part[1][d] + sh_part[2][d] + sh_part[3][d];

    // cold path: fold in overflow rows (ovf[0]==0 in practice)
    const int novf = ovf[0];
    if (novf > 0) {
        for (int j = 0; j < novf; ++j) {
            if (ovf[1 + 2 * j] == c) sum += z[(size_t)ovf[2 + 2 * j] * kD + d];
        }
    }

    const float mean   = sum / fmaxf((float)cntc, 1.0f);
    const float nrm    = sqrtf(block_sum256(mean * mean));
    const float mean_n = mean / fmaxf(nrm, kEps);

    const float p    = protos[c * kD + d];
    const float e    = kMom * p + (1.0f - kMom) * mean_n;
    const float nrm2 = sqrtf(block_sum256(e * e));
    const float ema  = e / fmaxf(nrm2, kEps);

    const float cand = (initialized[c] != 0) ? ema : mean_n;
    __builtin_nontemporal_store((cntc > 0) ? cand : p, &out[c * kD + d]);
}

// ================= fallback path (tiny ws): atomics into d_out ==============
__global__ void k_atomic_accum(const float* __restrict__ z,
                               const int* __restrict__ labels, int n,
                               float* __restrict__ sums, int* __restrict__ counts) {
    const int i = blockIdx.x;
    const int d = threadIdx.x;
    if (i >= n) return;
    const int lab = labels[i];
    atomicAdd(&sums[lab * kD + d], z[i * kD + d]);
    if (d == 0) atomicAdd(&counts[lab], 1);
}

__global__ void k_finalize_from_sums(const float* __restrict__ protos,
                                     const int* __restrict__ initialized,
                                     const int* __restrict__ counts,
                                     float* __restrict__ out) {
    const int c = blockIdx.x;
    const int d = threadIdx.x;
    const int cntc = counts[c];
    const float sum = out[c * kD + d];

    const float mean   = sum / fmaxf((float)cntc, 1.0f);
    const float nrm    = sqrtf(block_sum256(mean * mean));
    const float mean_n = mean / fmaxf(nrm, kEps);

    const float p    = protos[c * kD + d];
    const float e    = kMom * p + (1.0f - kMom) * mean_n;
    const float nrm2 = sqrtf(block_sum256(e * e));
    const float ema  = e / fmaxf(nrm2, kEps);

    const float cand = (initialized[c] != 0) ? ema : mean_n;
    out[c * kD + d] = (cntc > 0) ? cand : p;
}

extern "C" void kernel_launch(void* const* d_in, const int* in_sizes, int n_in,
                              void* d_out, int out_size, void* d_ws, size_t ws_size,
                              hipStream_t stream) {
    const float* z           = (const float*)d_in[0];
    const float* protos      = (const float*)d_in[1];
    const int*   initialized = (const int*)d_in[2];
    const int*   labels      = (const int*)d_in[3];
    const int n = in_sizes[3];          // N (labels count)
    float* out = (float*)d_out;

    // ws layout (4-byte units):
    //   [cnt: 1024*kCntS (padded)][ovf: 8 + 2N][idx: kC*kCap]
    int* ws  = (int*)d_ws;
    int* cnt = ws;                               // [1024*kCntS]
    int* ovf = ws + 1024 * kCntS;                // [8 + 2N]
    int* idx = ws + 1024 * kCntS + 8 + 2 * n;    // [kC*kCap]
    const size_t need = (size_t)(1024 * kCntS + 8 + 2 * (size_t)n
                                 + (size_t)kC * kCap) * sizeof(int);

    if (ws_size >= need) {
        // zero padded counters + overflow count (64.2 KB)
        (void)hipMemsetAsync(ws, 0, (size_t)(1024 * kCntS + 8) * sizeof(int),
                             stream);
        const int threads = (n + 3) / 4;
        const int blocks = (threads + 255) / 256;
        k_scatter<<<blocks, 256, 0, stream>>>(labels, n, cnt, idx, ovf);
        k_reduce <<<kC, kD, 0, stream>>>(z, protos, initialized, cnt, idx,
                                         ovf, out);
    } else {
        // fallback: accumulate sums directly in d_out with float atomics
        int* counts = ws;               // 4 KB
        (void)hipMemsetAsync(counts, 0, kC * sizeof(int), stream);
        (void)hipMemsetAsync(out, 0, (size_t)kC * kD * sizeof(float), stream);
        k_atomic_accum<<<n, kD, 0, stream>>>(z, labels, n, out, counts);
        k_finalize_from_sums<<<kC, kD, 0, stream>>>(protos, initialized, counts, out);
    }
}

// Round 11
// 37.601 us; speedup vs baseline: 2.4859x; 1.1547x over previous
//
#include <hip/hip_runtime.h>
#include <math.h>

// Problem constants (match reference)
static constexpr int   kC      = 1000;   // NUM_CLASSES
static constexpr int   kStripe = 1024;   // labels per scatter block = per-(block,class) capacity
static constexpr int   kD      = 256;    // EMBED_DIM
static constexpr int   kCap    = 1024;   // fallback path bin capacity
static constexpr int   kCntS   = 16;     // fallback counter stride
static constexpr float kMom    = 0.995f; // MOMENTUM
static constexpr float kEps    = 1e-12f; // F.normalize eps

typedef float f32x4 __attribute__((ext_vector_type(4)));

__device__ __forceinline__ f32x4 nt_load4(const float* p) {
    return __builtin_nontemporal_load((const f32x4*)p);
}

// ---- block-wide sum over 256 threads (4 waves of 64) ----
__device__ __forceinline__ float block_sum256(float v) {
    __shared__ float lds[4];
    #pragma unroll
    for (int off = 32; off > 0; off >>= 1) v += __shfl_down(v, off, 64);
    __syncthreads();                       // protect lds from prior call's reads
    if ((threadIdx.x & 63) == 0) lds[threadIdx.x >> 6] = v;
    __syncthreads();
    return lds[0] + lds[1] + lds[2] + lds[3];
}

// ============ pass 1: atomic-free stripe scatter (no memset needed) =========
// Block b owns label window [b*1024, (b+1)*1024). Per-class counts live in
// LDS (fast LDS atomics, zero cross-block contention); row indices go to the
// block's PRIVATE stripe region idx[b][c][0..1024). Capacity is exact, so no
// overflow valve; nothing requires pre-zeroed global memory.
__global__ void __launch_bounds__(256)
k_scatter2(const int* __restrict__ labels, int n,
           unsigned short* __restrict__ cntmat,  // [B][kC]
           int* __restrict__ idx) {              // [B][kC][kStripe]
    __shared__ unsigned int hcnt[kC];
    const int b   = blockIdx.x;
    const int tid = threadIdx.x;

    for (int c = tid; c < kC; c += 256) hcnt[c] = 0;
    __syncthreads();

    const int base = b * kStripe;
    const int m = min(kStripe, n - base);
    const size_t sbase = (size_t)b * kC * kStripe;

    if (m == kStripe) {
        const int4 l4 = ((const int4*)(labels + base))[tid];
        #pragma unroll
        for (int k = 0; k < 4; ++k) {
            const int lab = (&l4.x)[k];
            const unsigned int p = atomicAdd(&hcnt[lab], 1u);
            idx[sbase + (size_t)lab * kStripe + p] = base + tid * 4 + k;
        }
    } else {
        for (int j = tid; j < m; j += 256) {
            const int lab = labels[base + j];
            const unsigned int p = atomicAdd(&hcnt[lab], 1u);
            idx[sbase + (size_t)lab * kStripe + p] = base + j;
        }
    }
    __syncthreads();
    for (int c = tid; c < kC; c += 256)
        cntmat[(size_t)b * kC + c] = (unsigned short)hcnt[c];
}

// ============ pass 2: stripe-compact + gather-sum + fused epilogue ==========
__global__ void __launch_bounds__(256, 4)
k_reduce2(const float* __restrict__ z, const float* __restrict__ protos,
          const int* __restrict__ initialized,
          const unsigned short* __restrict__ cntmat, int B,
          const int* __restrict__ idx, float* __restrict__ out) {
    __shared__ int          sh_idx[kStripe];
    __shared__ float        sh_part[4][kD];
    __shared__ unsigned int s_pfx[256];

    const int c    = blockIdx.x;
    const int tid  = threadIdx.x;
    const int wave = tid >> 6;
    const int lane = tid & 63;

    // per-stripe count for this class (tid >= B contributes 0)
    const unsigned int myc = (tid < B) ? cntmat[(size_t)tid * kC + c] : 0u;

    // 256-wide inclusive scan -> exclusive prefix + total
    s_pfx[tid] = myc;
    __syncthreads();
    for (int off = 1; off < 256; off <<= 1) {
        const unsigned int add = (tid >= off) ? s_pfx[tid - off] : 0u;
        __syncthreads();
        s_pfx[tid] += add;
        __syncthreads();
    }
    const unsigned int T  = s_pfx[255];
    const unsigned int ex = s_pfx[tid] - myc;

    f32x4 acc0 = {0.f, 0.f, 0.f, 0.f};
    f32x4 acc1 = {0.f, 0.f, 0.f, 0.f};

    // chunked staging (single iteration for typical T~131; generic for safety)
    for (unsigned int cb = 0; cb < T; cb += kStripe) {
        __syncthreads();
        if (myc > 0) {
            const size_t sb = ((size_t)tid * kC + c) * kStripe;
            for (unsigned int q = 0; q < myc; ++q) {
                const unsigned int g = ex + q;
                if (g >= cb && g < cb + kStripe) sh_idx[g - cb] = idx[sb + q];
            }
        }
        __syncthreads();

        const int mm = (int)min((unsigned int)kStripe, T - cb);
        int r = wave;
        for (; r + 28 < mm; r += 32) {      // 8 independent 1KB rows in flight
            const int i0 = sh_idx[r +  0]; const int i1 = sh_idx[r +  4];
            const int i2 = sh_idx[r +  8]; const int i3 = sh_idx[r + 12];
            const int i4 = sh_idx[r + 16]; const int i5 = sh_idx[r + 20];
            const int i6 = sh_idx[r + 24]; const int i7 = sh_idx[r + 28];
            const f32x4 a0 = nt_load4(z + (size_t)i0 * kD + lane * 4);
            const f32x4 a1 = nt_load4(z + (size_t)i1 * kD + lane * 4);
            const f32x4 a2 = nt_load4(z + (size_t)i2 * kD + lane * 4);
            const f32x4 a3 = nt_load4(z + (size_t)i3 * kD + lane * 4);
            const f32x4 a4 = nt_load4(z + (size_t)i4 * kD + lane * 4);
            const f32x4 a5 = nt_load4(z + (size_t)i5 * kD + lane * 4);
            const f32x4 a6 = nt_load4(z + (size_t)i6 * kD + lane * 4);
            const f32x4 a7 = nt_load4(z + (size_t)i7 * kD + lane * 4);
            acc0 += a0 + a1;
            acc1 += a2 + a3;
            acc0 += a4 + a5;
            acc1 += a6 + a7;
        }
        for (; r < mm; r += 4) {
            acc0 += nt_load4(z + (size_t)sh_idx[r] * kD + lane * 4);
        }
    }
    acc0 += acc1;

    __syncthreads();                        // sh_idx readers done (last chunk)
    ((f32x4*)&sh_part[wave][lane * 4])[0] = acc0;
    __syncthreads();

    const int d = tid;
    const float sum = sh_part[0][d] + sh_part[1][d] + sh_part[2][d] + sh_part[3][d];
    const int cntc = (int)T;

    const float mean   = sum / fmaxf((float)cntc, 1.0f);
    const float nrm    = sqrtf(block_sum256(mean * mean));
    const float mean_n = mean / fmaxf(nrm, kEps);

    const float p    = protos[c * kD + d];
    const float e    = kMom * p + (1.0f - kMom) * mean_n;
    const float nrm2 = sqrtf(block_sum256(e * e));
    const float ema  = e / fmaxf(nrm2, kEps);

    const float cand = (initialized[c] != 0) ? ema : mean_n;
    __builtin_nontemporal_store((cntc > 0) ? cand : p, &out[c * kD + d]);
}

// ================= fallback: round-10 padded-atomic pipeline ================
__global__ void k_scatter(const int* __restrict__ labels, int n,
                          int* __restrict__ cnt /* stride kCntS */,
                          int* __restrict__ idx,
                          int* __restrict__ ovf) {
    const int t = blockIdx.x * 256 + threadIdx.x;
    const int i0 = t * 4;
    if (i0 >= n) return;
    const int lim = min(4, n - i0);
    for (int k = 0; k < lim; ++k) {
        const int i = i0 + k;
        const int lab = labels[i];
        const int p = atomicAdd(&cnt[lab * kCntS], 1);
        if (p < kCap) {
            idx[(size_t)lab * kCap + p] = i;
        } else {
            const int q = atomicAdd(&ovf[0], 1);
            ovf[1 + 2 * q] = lab; ovf[2 + 2 * q] = i;
        }
    }
}

__global__ void __launch_bounds__(256, 4)
k_reduce(const float* __restrict__ z, const float* __restrict__ protos,
         const int* __restrict__ initialized, const int* __restrict__ cnt,
         const int* __restrict__ idx, const int* __restrict__ ovf,
         float* __restrict__ out) {
    __shared__ int   sh_idx[kCap];
    __shared__ float sh_part[4][kD];

    const int c    = blockIdx.x;
    const int tid  = threadIdx.x;
    const int wave = tid >> 6;
    const int lane = tid & 63;

    const int cntc = cnt[c * kCntS];
    const int m    = min(cntc, kCap);
    const int* __restrict__ cidx = idx + (size_t)c * kCap;

    for (int j = tid; j < m; j += 256) sh_idx[j] = cidx[j];
    __syncthreads();

    f32x4 acc0 = {0.f, 0.f, 0.f, 0.f};
    f32x4 acc1 = {0.f, 0.f, 0.f, 0.f};
    int r = wave;
    for (; r + 28 < m; r += 32) {
        const int i0 = sh_idx[r +  0]; const int i1 = sh_idx[r +  4];
        const int i2 = sh_idx[r +  8]; const int i3 = sh_idx[r + 12];
        const int i4 = sh_idx[r + 16]; const int i5 = sh_idx[r + 20];
        const int i6 = sh_idx[r + 24]; const int i7 = sh_idx[r + 28];
        const f32x4 a0 = nt_load4(z + (size_t)i0 * kD + lane * 4);
        const f32x4 a1 = nt_load4(z + (size_t)i1 * kD + lane * 4);
        const f32x4 a2 = nt_load4(z + (size_t)i2 * kD + lane * 4);
        const f32x4 a3 = nt_load4(z + (size_t)i3 * kD + lane * 4);
        const f32x4 a4 = nt_load4(z + (size_t)i4 * kD + lane * 4);
        const f32x4 a5 = nt_load4(z + (size_t)i5 * kD + lane * 4);
        const f32x4 a6 = nt_load4(z + (size_t)i6 * kD + lane * 4);
        const f32x4 a7 = nt_load4(z + (size_t)i7 * kD + lane * 4);
        acc0 += a0 + a1; acc1 += a2 + a3;
        acc0 += a4 + a5; acc1 += a6 + a7;
    }
    for (; r < m; r += 4) acc0 += nt_load4(z + (size_t)sh_idx[r] * kD + lane * 4);
    acc0 += acc1;

    ((f32x4*)&sh_part[wave][lane * 4])[0] = acc0;
    __syncthreads();

    const int d = tid;
    float sum = sh_part[0][d] + sh_part[1][d] + sh_part[2][d] + sh_part[3][d];
    const int novf = ovf[0];
    if (novf > 0) {
        for (int j = 0; j < novf; ++j)
            if (ovf[1 + 2 * j] == c) sum += z[(size_t)ovf[2 + 2 * j] * kD + d];
    }

    const float mean   = sum / fmaxf((float)cntc, 1.0f);
    const float nrm    = sqrtf(block_sum256(mean * mean));
    const float mean_n = mean / fmaxf(nrm, kEps);
    const float p    = protos[c * kD + d];
    const float e    = kMom * p + (1.0f - kMom) * mean_n;
    const float nrm2 = sqrtf(block_sum256(e * e));
    const float ema  = e / fmaxf(nrm2, kEps);
    const float cand = (initialized[c] != 0) ? ema : mean_n;
    __builtin_nontemporal_store((cntc > 0) ? cand : p, &out[c * kD + d]);
}

extern "C" void kernel_launch(void* const* d_in, const int* in_sizes, int n_in,
                              void* d_out, int out_size, void* d_ws, size_t ws_size,
                              hipStream_t stream) {
    const float* z           = (const float*)d_in[0];
    const float* protos      = (const float*)d_in[1];
    const int*   initialized = (const int*)d_in[2];
    const int*   labels      = (const int*)d_in[3];
    const int n = in_sizes[3];          // N (labels count)
    float* out = (float*)d_out;

    const int B = (n + kStripe - 1) / kStripe;   // scatter blocks (128 at N=131072)
    // new-path ws: [cntmat: B*kC u16, 256B-aligned][idx: B*kC*kStripe int]
    const size_t cnt_bytes = (((size_t)B * kC * sizeof(unsigned short)) + 255) & ~(size_t)255;
    const size_t need2 = cnt_bytes + (size_t)B * kC * kStripe * sizeof(int);

    if (B <= 256 && ws_size >= need2) {
        unsigned short* cntmat = (unsigned short*)d_ws;
        int* idx = (int*)((char*)d_ws + cnt_bytes);
        k_scatter2<<<B, 256, 0, stream>>>(labels, n, cntmat, idx);
        k_reduce2 <<<kC, 256, 0, stream>>>(z, protos, initialized, cntmat, B,
                                           idx, out);
        return;
    }

    // fallback: round-10 padded-atomic pipeline
    int* ws  = (int*)d_ws;
    int* cnt = ws;                               // [1024*kCntS]
    int* ovf = ws + 1024 * kCntS;                // [8 + 2N]
    int* idx = ws + 1024 * kCntS + 8 + 2 * n;    // [kC*kCap]
    (void)hipMemsetAsync(ws, 0, (size_t)(1024 * kCntS + 8) * sizeof(int), stream);
    const int threads = (n + 3) / 4;
    const int blocks = (threads + 255) / 256;
    k_scatter<<<blocks, 256, 0, stream>>>(labels, n, cnt, idx, ovf);
    k_reduce <<<kC, 256, 0, stream>>>(z, protos, initialized, cnt, idx, ovf, out);
}

// Round 12
// 36.993 us; speedup vs baseline: 2.5268x; 1.0164x over previous
//
#include <hip/hip_runtime.h>
#include <math.h>

// Problem constants (match reference)
static constexpr int   kC      = 1000;   // NUM_CLASSES
static constexpr int   kStripe = 512;    // labels per scatter block (u16 local idx)
static constexpr int   kD      = 256;    // EMBED_DIM
static constexpr int   kCap    = 1024;   // fallback path bin capacity
static constexpr int   kCntS   = 16;     // fallback counter stride
static constexpr float kMom    = 0.995f; // MOMENTUM
static constexpr float kEps    = 1e-12f; // F.normalize eps

typedef float f32x4 __attribute__((ext_vector_type(4)));

__device__ __forceinline__ f32x4 nt_load4(const float* p) {
    return __builtin_nontemporal_load((const f32x4*)p);
}

// ---- block-wide sum over 256 threads (4 waves of 64) ----
__device__ __forceinline__ float block_sum256(float v) {
    __shared__ float lds[4];
    #pragma unroll
    for (int off = 32; off > 0; off >>= 1) v += __shfl_down(v, off, 64);
    __syncthreads();                       // protect lds from prior call's reads
    if ((threadIdx.x & 63) == 0) lds[threadIdx.x >> 6] = v;
    __syncthreads();
    return lds[0] + lds[1] + lds[2] + lds[3];
}

// ============ pass 1: atomic-free stripe scatter (no memset needed) =========
// Block b owns label window [b*512, (b+1)*512). Per-class counts in LDS;
// stripe-LOCAL u16 indices go to the block's private region idx16[b][c][..].
// Capacity exact (a stripe has 512 labels), so no overflow path at all.
__global__ void __launch_bounds__(256)
k_scatter2(const int* __restrict__ labels, int n,
           unsigned short* __restrict__ cntmat,   // [B][kC]
           unsigned short* __restrict__ idx16) {  // [B][kC][kStripe]
    __shared__ unsigned int hcnt[kC];
    const int b   = blockIdx.x;
    const int tid = threadIdx.x;

    for (int c = tid; c < kC; c += 256) hcnt[c] = 0;
    __syncthreads();

    const int base = b * kStripe;
    const int m = min(kStripe, n - base);
    const size_t sbase = (size_t)b * kC * kStripe;

    if (m == kStripe) {
        const int2 l2 = ((const int2*)(labels + base))[tid];
        #pragma unroll
        for (int k = 0; k < 2; ++k) {
            const int lab = (&l2.x)[k];
            const unsigned int p = atomicAdd(&hcnt[lab], 1u);
            idx16[sbase + (size_t)lab * kStripe + p] =
                (unsigned short)(tid * 2 + k);
        }
    } else {
        for (int j = tid; j < m; j += 256) {
            const int lab = labels[base + j];
            const unsigned int p = atomicAdd(&hcnt[lab], 1u);
            idx16[sbase + (size_t)lab * kStripe + p] = (unsigned short)j;
        }
    }
    __syncthreads();
    for (int c = tid; c < kC; c += 256)
        cntmat[(size_t)b * kC + c] = (unsigned short)hcnt[c];
}

// ============ pass 2: stripe-compact + gather-sum + fused epilogue ==========
// One block (4 waves) per class. Shfl-based scan (2 barriers, was 16).
__global__ void __launch_bounds__(256)
k_reduce2(const float* __restrict__ z, const float* __restrict__ protos,
          const int* __restrict__ initialized,
          const unsigned short* __restrict__ cntmat, int B,
          const unsigned short* __restrict__ idx16, float* __restrict__ out) {
    __shared__ int          sh_idx[1024];
    __shared__ float        sh_part[4][kD];
    __shared__ unsigned int wtot[4];

    const int c    = blockIdx.x;
    const int tid  = threadIdx.x;
    const int wave = tid >> 6;
    const int lane = tid & 63;

    // per-stripe count for this class (tid >= B contributes 0); B <= 256
    const unsigned int myc = (tid < B) ? cntmat[(size_t)tid * kC + c] : 0u;

    // per-wave inclusive shfl-scan + wave-total combine (2 barriers total)
    unsigned int s = myc;
    #pragma unroll
    for (int off = 1; off < 64; off <<= 1) {
        const unsigned int t = __shfl_up(s, off, 64);
        if (lane >= off) s += t;
    }
    if (lane == 63) wtot[wave] = s;
    __syncthreads();
    unsigned int wbase = 0;
    #pragma unroll
    for (int w = 0; w < 4; ++w) wbase += (w < wave) ? wtot[w] : 0u;
    const unsigned int T  = wtot[0] + wtot[1] + wtot[2] + wtot[3];
    const unsigned int ex = wbase + s - myc;

    f32x4 acc0 = {0.f, 0.f, 0.f, 0.f};
    f32x4 acc1 = {0.f, 0.f, 0.f, 0.f};

    // chunked staging (single iteration for typical T~131; generic for safety)
    for (unsigned int cb = 0; cb < T; cb += 1024) {
        __syncthreads();                    // sh_idx reuse guard
        if (myc > 0) {
            const size_t sb = ((size_t)tid * kC + c) * kStripe;
            const int rowbase = tid * kStripe;
            for (unsigned int q = 0; q < myc; ++q) {
                const unsigned int g = ex + q;
                if (g >= cb && g < cb + 1024)
                    sh_idx[g - cb] = rowbase + (int)idx16[sb + q];
            }
        }
        __syncthreads();

        const int mm = (int)min(1024u, T - cb);
        int r = wave;
        for (; r + 28 < mm; r += 32) {      // 8 independent 1KB rows in flight
            const int i0 = sh_idx[r +  0]; const int i1 = sh_idx[r +  4];
            const int i2 = sh_idx[r +  8]; const int i3 = sh_idx[r + 12];
            const int i4 = sh_idx[r + 16]; const int i5 = sh_idx[r + 20];
            const int i6 = sh_idx[r + 24]; const int i7 = sh_idx[r + 28];
            const f32x4 a0 = nt_load4(z + (size_t)i0 * kD + lane * 4);
            const f32x4 a1 = nt_load4(z + (size_t)i1 * kD + lane * 4);
            const f32x4 a2 = nt_load4(z + (size_t)i2 * kD + lane * 4);
            const f32x4 a3 = nt_load4(z + (size_t)i3 * kD + lane * 4);
            const f32x4 a4 = nt_load4(z + (size_t)i4 * kD + lane * 4);
            const f32x4 a5 = nt_load4(z + (size_t)i5 * kD + lane * 4);
            const f32x4 a6 = nt_load4(z + (size_t)i6 * kD + lane * 4);
            const f32x4 a7 = nt_load4(z + (size_t)i7 * kD + lane * 4);
            acc0 += a0 + a1;
            acc1 += a2 + a3;
            acc0 += a4 + a5;
            acc1 += a6 + a7;
        }
        for (; r + 12 < mm; r += 16) {      // 4-deep mid-tier (tail rows)
            const int i0 = sh_idx[r +  0]; const int i1 = sh_idx[r +  4];
            const int i2 = sh_idx[r +  8]; const int i3 = sh_idx[r + 12];
            const f32x4 a0 = nt_load4(z + (size_t)i0 * kD + lane * 4);
            const f32x4 a1 = nt_load4(z + (size_t)i1 * kD + lane * 4);
            const f32x4 a2 = nt_load4(z + (size_t)i2 * kD + lane * 4);
            const f32x4 a3 = nt_load4(z + (size_t)i3 * kD + lane * 4);
            acc0 += a0 + a1;
            acc1 += a2 + a3;
        }
        for (; r < mm; r += 4) {
            acc0 += nt_load4(z + (size_t)sh_idx[r] * kD + lane * 4);
        }
    }
    acc0 += acc1;

    __syncthreads();                        // sh_idx readers done (last chunk)
    ((f32x4*)&sh_part[wave][lane * 4])[0] = acc0;
    __syncthreads();

    const int d = tid;
    const float sum = sh_part[0][d] + sh_part[1][d] + sh_part[2][d] + sh_part[3][d];
    const int cntc = (int)T;

    const float mean   = sum / fmaxf((float)cntc, 1.0f);
    const float nrm    = sqrtf(block_sum256(mean * mean));
    const float mean_n = mean / fmaxf(nrm, kEps);

    const float p    = protos[c * kD + d];
    const float e    = kMom * p + (1.0f - kMom) * mean_n;
    const float nrm2 = sqrtf(block_sum256(e * e));
    const float ema  = e / fmaxf(nrm2, kEps);

    const float cand = (initialized[c] != 0) ? ema : mean_n;
    __builtin_nontemporal_store((cntc > 0) ? cand : p, &out[c * kD + d]);
}

// ================= fallback: round-10 padded-atomic pipeline ================
__global__ void k_scatter(const int* __restrict__ labels, int n,
                          int* __restrict__ cnt /* stride kCntS */,
                          int* __restrict__ idx,
                          int* __restrict__ ovf) {
    const int t = blockIdx.x * 256 + threadIdx.x;
    const int i0 = t * 4;
    if (i0 >= n) return;
    const int lim = min(4, n - i0);
    for (int k = 0; k < lim; ++k) {
        const int i = i0 + k;
        const int lab = labels[i];
        const int p = atomicAdd(&cnt[lab * kCntS], 1);
        if (p < kCap) {
            idx[(size_t)lab * kCap + p] = i;
        } else {
            const int q = atomicAdd(&ovf[0], 1);
            ovf[1 + 2 * q] = lab; ovf[2 + 2 * q] = i;
        }
    }
}

__global__ void __launch_bounds__(256, 4)
k_reduce(const float* __restrict__ z, const float* __restrict__ protos,
         const int* __restrict__ initialized, const int* __restrict__ cnt,
         const int* __restrict__ idx, const int* __restrict__ ovf,
         float* __restrict__ out) {
    __shared__ int   sh_idx[kCap];
    __shared__ float sh_part[4][kD];

    const int c    = blockIdx.x;
    const int tid  = threadIdx.x;
    const int wave = tid >> 6;
    const int lane = tid & 63;

    const int cntc = cnt[c * kCntS];
    const int m    = min(cntc, kCap);
    const int* __restrict__ cidx = idx + (size_t)c * kCap;

    for (int j = tid; j < m; j += 256) sh_idx[j] = cidx[j];
    __syncthreads();

    f32x4 acc0 = {0.f, 0.f, 0.f, 0.f};
    f32x4 acc1 = {0.f, 0.f, 0.f, 0.f};
    int r = wave;
    for (; r + 28 < m; r += 32) {
        const int i0 = sh_idx[r +  0]; const int i1 = sh_idx[r +  4];
        const int i2 = sh_idx[r +  8]; const int i3 = sh_idx[r + 12];
        const int i4 = sh_idx[r + 16]; const int i5 = sh_idx[r + 20];
        const int i6 = sh_idx[r + 24]; const int i7 = sh_idx[r + 28];
        const f32x4 a0 = nt_load4(z + (size_t)i0 * kD + lane * 4);
        const f32x4 a1 = nt_load4(z + (size_t)i1 * kD + lane * 4);
        const f32x4 a2 = nt_load4(z + (size_t)i2 * kD + lane * 4);
        const f32x4 a3 = nt_load4(z + (size_t)i3 * kD + lane * 4);
        const f32x4 a4 = nt_load4(z + (size_t)i4 * kD + lane * 4);
        const f32x4 a5 = nt_load4(z + (size_t)i5 * kD + lane * 4);
        const f32x4 a6 = nt_load4(z + (size_t)i6 * kD + lane * 4);
        const f32x4 a7 = nt_load4(z + (size_t)i7 * kD + lane * 4);
        acc0 += a0 + a1; acc1 += a2 + a3;
        acc0 += a4 + a5; acc1 += a6 + a7;
    }
    for (; r < m; r += 4) acc0 += nt_load4(z + (size_t)sh_idx[r] * kD + lane * 4);
    acc0 += acc1;

    ((f32x4*)&sh_part[wave][lane * 4])[0] = acc0;
    __syncthreads();

    const int d = tid;
    float sum = sh_part[0][d] + sh_part[1][d] + sh_part[2][d] + sh_part[3][d];
    const int novf = ovf[0];
    if (novf > 0) {
        for (int j = 0; j < novf; ++j)
            if (ovf[1 + 2 * j] == c) sum += z[(size_t)ovf[2 + 2 * j] * kD + d];
    }

    const float mean   = sum / fmaxf((float)cntc, 1.0f);
    const float nrm    = sqrtf(block_sum256(mean * mean));
    const float mean_n = mean / fmaxf(nrm, kEps);
    const float p    = protos[c * kD + d];
    const float e    = kMom * p + (1.0f - kMom) * mean_n;
    const float nrm2 = sqrtf(block_sum256(e * e));
    const float ema  = e / fmaxf(nrm2, kEps);
    const float cand = (initialized[c] != 0) ? ema : mean_n;
    __builtin_nontemporal_store((cntc > 0) ? cand : p, &out[c * kD + d]);
}

extern "C" void kernel_launch(void* const* d_in, const int* in_sizes, int n_in,
                              void* d_out, int out_size, void* d_ws, size_t ws_size,
                              hipStream_t stream) {
    const float* z           = (const float*)d_in[0];
    const float* protos      = (const float*)d_in[1];
    const int*   initialized = (const int*)d_in[2];
    const int*   labels      = (const int*)d_in[3];
    const int n = in_sizes[3];          // N (labels count)
    float* out = (float*)d_out;

    const int B = (n + kStripe - 1) / kStripe;   // 256 at N=131072
    // new-path ws: [cntmat: B*kC u16, 256B-aligned][idx16: B*kC*kStripe u16]
    const size_t cnt_bytes = (((size_t)B * kC * sizeof(unsigned short)) + 255)
                             & ~(size_t)255;
    const size_t need2 = cnt_bytes
                       + (size_t)B * kC * kStripe * sizeof(unsigned short);

    if (B <= 256 && ws_size >= need2) {
        unsigned short* cntmat = (unsigned short*)d_ws;
        unsigned short* idx16  = (unsigned short*)((char*)d_ws + cnt_bytes);
        k_scatter2<<<B, 256, 0, stream>>>(labels, n, cntmat, idx16);
        k_reduce2 <<<kC, 256, 0, stream>>>(z, protos, initialized, cntmat, B,
                                           idx16, out);
        return;
    }

    // fallback: round-10 padded-atomic pipeline
    int* ws  = (int*)d_ws;
    int* cnt = ws;                               // [1024*kCntS]
    int* ovf = ws + 1024 * kCntS;                // [8 + 2N]
    int* idx = ws + 1024 * kCntS + 8 + 2 * n;    // [kC*kCap]
    (void)hipMemsetAsync(ws, 0, (size_t)(1024 * kCntS + 8) * sizeof(int), stream);
    const int threads = (n + 3) / 4;
    const int blocks = (threads + 255) / 256;
    k_scatter<<<blocks, 256, 0, stream>>>(labels, n, cnt, idx, ovf);
    k_reduce <<<kC, 256, 0, stream>>>(z, protos, initialized, cnt, idx, ovf, out);
}

// Round 13
// 36.153 us; speedup vs baseline: 2.5855x; 1.0232x over previous
//
#include <hip/hip_runtime.h>
#include <math.h>

// Problem constants (match reference)
static constexpr int   kC      = 1000;   // NUM_CLASSES
static constexpr int   kStripe = 512;    // labels per scatter block (u16 local idx)
static constexpr int   kD      = 256;    // EMBED_DIM
static constexpr int   kCap    = 1024;   // fallback path bin capacity
static constexpr int   kCntS   = 16;     // fallback counter stride
static constexpr float kMom    = 0.995f; // MOMENTUM
static constexpr float kEps    = 1e-12f; // F.normalize eps

typedef float f32x4 __attribute__((ext_vector_type(4)));

// Cached (non-NT) vector load: z fits in the 256MB Infinity Cache, and graph
// replays re-read it — NT hints were defeating L3 residency.
__device__ __forceinline__ f32x4 ld4(const float* p) {
    return *(const f32x4*)p;
}

// ---- block-wide sum over 256 threads (4 waves of 64) ----
__device__ __forceinline__ float block_sum256(float v) {
    __shared__ float lds[4];
    #pragma unroll
    for (int off = 32; off > 0; off >>= 1) v += __shfl_down(v, off, 64);
    __syncthreads();                       // protect lds from prior call's reads
    if ((threadIdx.x & 63) == 0) lds[threadIdx.x >> 6] = v;
    __syncthreads();
    return lds[0] + lds[1] + lds[2] + lds[3];
}

// ============ pass 1: atomic-free stripe scatter (no memset needed) =========
__global__ void __launch_bounds__(256)
k_scatter2(const int* __restrict__ labels, int n,
           unsigned short* __restrict__ cntmat,   // [B][kC]
           unsigned short* __restrict__ idx16) {  // [B][kC][kStripe]
    __shared__ unsigned int hcnt[kC];
    const int b   = blockIdx.x;
    const int tid = threadIdx.x;

    for (int c = tid; c < kC; c += 256) hcnt[c] = 0;
    __syncthreads();

    const int base = b * kStripe;
    const int m = min(kStripe, n - base);
    const size_t sbase = (size_t)b * kC * kStripe;

    if (m == kStripe) {
        const int2 l2 = ((const int2*)(labels + base))[tid];
        #pragma unroll
        for (int k = 0; k < 2; ++k) {
            const int lab = (&l2.x)[k];
            const unsigned int p = atomicAdd(&hcnt[lab], 1u);
            idx16[sbase + (size_t)lab * kStripe + p] =
                (unsigned short)(tid * 2 + k);
        }
    } else {
        for (int j = tid; j < m; j += 256) {
            const int lab = labels[base + j];
            const unsigned int p = atomicAdd(&hcnt[lab], 1u);
            idx16[sbase + (size_t)lab * kStripe + p] = (unsigned short)j;
        }
    }
    __syncthreads();
    for (int c = tid; c < kC; c += 256)
        cntmat[(size_t)b * kC + c] = (unsigned short)hcnt[c];
}

// ============ pass 2: stripe-compact + gather-sum + fused epilogue ==========
__global__ void __launch_bounds__(256)
k_reduce2(const float* __restrict__ z, const float* __restrict__ protos,
          const int* __restrict__ initialized,
          const unsigned short* __restrict__ cntmat, int B,
          const unsigned short* __restrict__ idx16, float* __restrict__ out) {
    __shared__ int          sh_idx[1024];
    __shared__ float        sh_part[4][kD];
    __shared__ unsigned int wtot[4];

    const int c    = blockIdx.x;
    const int tid  = threadIdx.x;
    const int wave = tid >> 6;
    const int lane = tid & 63;

    // per-stripe count for this class (tid >= B contributes 0); B <= 256
    const unsigned int myc = (tid < B) ? cntmat[(size_t)tid * kC + c] : 0u;

    // per-wave inclusive shfl-scan + wave-total combine (2 barriers total)
    unsigned int s = myc;
    #pragma unroll
    for (int off = 1; off < 64; off <<= 1) {
        const unsigned int t = __shfl_up(s, off, 64);
        if (lane >= off) s += t;
    }
    if (lane == 63) wtot[wave] = s;
    __syncthreads();
    unsigned int wbase = 0;
    #pragma unroll
    for (int w = 0; w < 4; ++w) wbase += (w < wave) ? wtot[w] : 0u;
    const unsigned int T  = wtot[0] + wtot[1] + wtot[2] + wtot[3];
    const unsigned int ex = wbase + s - myc;

    f32x4 acc0 = {0.f, 0.f, 0.f, 0.f};
    f32x4 acc1 = {0.f, 0.f, 0.f, 0.f};

    // chunked staging (single iteration for typical T~131; generic for safety)
    for (unsigned int cb = 0; cb < T; cb += 1024) {
        __syncthreads();                    // sh_idx reuse guard
        if (myc > 0) {
            const size_t sb = ((size_t)tid * kC + c) * kStripe;
            const int rowbase = tid * kStripe;
            for (unsigned int q = 0; q < myc; ++q) {
                const unsigned int g = ex + q;
                if (g >= cb && g < cb + 1024)
                    sh_idx[g - cb] = rowbase + (int)idx16[sb + q];
            }
        }
        __syncthreads();

        const int mm = (int)min(1024u, T - cb);
        int r = wave;
        for (; r + 28 < mm; r += 32) {      // 8 independent 1KB rows in flight
            const int i0 = sh_idx[r +  0]; const int i1 = sh_idx[r +  4];
            const int i2 = sh_idx[r +  8]; const int i3 = sh_idx[r + 12];
            const int i4 = sh_idx[r + 16]; const int i5 = sh_idx[r + 20];
            const int i6 = sh_idx[r + 24]; const int i7 = sh_idx[r + 28];
            const f32x4 a0 = ld4(z + (size_t)i0 * kD + lane * 4);
            const f32x4 a1 = ld4(z + (size_t)i1 * kD + lane * 4);
            const f32x4 a2 = ld4(z + (size_t)i2 * kD + lane * 4);
            const f32x4 a3 = ld4(z + (size_t)i3 * kD + lane * 4);
            const f32x4 a4 = ld4(z + (size_t)i4 * kD + lane * 4);
            const f32x4 a5 = ld4(z + (size_t)i5 * kD + lane * 4);
            const f32x4 a6 = ld4(z + (size_t)i6 * kD + lane * 4);
            const f32x4 a7 = ld4(z + (size_t)i7 * kD + lane * 4);
            acc0 += a0 + a1;
            acc1 += a2 + a3;
            acc0 += a4 + a5;
            acc1 += a6 + a7;
        }
        for (; r + 12 < mm; r += 16) {      // 4-deep mid-tier (tail rows)
            const int i0 = sh_idx[r +  0]; const int i1 = sh_idx[r +  4];
            const int i2 = sh_idx[r +  8]; const int i3 = sh_idx[r + 12];
            const f32x4 a0 = ld4(z + (size_t)i0 * kD + lane * 4);
            const f32x4 a1 = ld4(z + (size_t)i1 * kD + lane * 4);
            const f32x4 a2 = ld4(z + (size_t)i2 * kD + lane * 4);
            const f32x4 a3 = ld4(z + (size_t)i3 * kD + lane * 4);
            acc0 += a0 + a1;
            acc1 += a2 + a3;
        }
        for (; r < mm; r += 4) {
            acc0 += ld4(z + (size_t)sh_idx[r] * kD + lane * 4);
        }
    }
    acc0 += acc1;

    __syncthreads();                        // sh_idx readers done (last chunk)
    ((f32x4*)&sh_part[wave][lane * 4])[0] = acc0;
    __syncthreads();

    const int d = tid;
    const float sum = sh_part[0][d] + sh_part[1][d] + sh_part[2][d] + sh_part[3][d];
    const int cntc = (int)T;

    const float mean   = sum / fmaxf((float)cntc, 1.0f);
    const float nrm    = sqrtf(block_sum256(mean * mean));
    const float mean_n = mean / fmaxf(nrm, kEps);

    const float p    = protos[c * kD + d];
    const float e    = kMom * p + (1.0f - kMom) * mean_n;
    const float nrm2 = sqrtf(block_sum256(e * e));
    const float ema  = e / fmaxf(nrm2, kEps);

    const float cand = (initialized[c] != 0) ? ema : mean_n;
    __builtin_nontemporal_store((cntc > 0) ? cand : p, &out[c * kD + d]);
}

// ================= fallback: round-10 padded-atomic pipeline ================
__global__ void k_scatter(const int* __restrict__ labels, int n,
                          int* __restrict__ cnt /* stride kCntS */,
                          int* __restrict__ idx,
                          int* __restrict__ ovf) {
    const int t = blockIdx.x * 256 + threadIdx.x;
    const int i0 = t * 4;
    if (i0 >= n) return;
    const int lim = min(4, n - i0);
    for (int k = 0; k < lim; ++k) {
        const int i = i0 + k;
        const int lab = labels[i];
        const int p = atomicAdd(&cnt[lab * kCntS], 1);
        if (p < kCap) {
            idx[(size_t)lab * kCap + p] = i;
        } else {
            const int q = atomicAdd(&ovf[0], 1);
            ovf[1 + 2 * q] = lab; ovf[2 + 2 * q] = i;
        }
    }
}

__global__ void __launch_bounds__(256, 4)
k_reduce(const float* __restrict__ z, const float* __restrict__ protos,
         const int* __restrict__ initialized, const int* __restrict__ cnt,
         const int* __restrict__ idx, const int* __restrict__ ovf,
         float* __restrict__ out) {
    __shared__ int   sh_idx[kCap];
    __shared__ float sh_part[4][kD];

    const int c    = blockIdx.x;
    const int tid  = threadIdx.x;
    const int wave = tid >> 6;
    const int lane = tid & 63;

    const int cntc = cnt[c * kCntS];
    const int m    = min(cntc, kCap);
    const int* __restrict__ cidx = idx + (size_t)c * kCap;

    for (int j = tid; j < m; j += 256) sh_idx[j] = cidx[j];
    __syncthreads();

    f32x4 acc0 = {0.f, 0.f, 0.f, 0.f};
    f32x4 acc1 = {0.f, 0.f, 0.f, 0.f};
    int r = wave;
    for (; r + 28 < m; r += 32) {
        const int i0 = sh_idx[r +  0]; const int i1 = sh_idx[r +  4];
        const int i2 = sh_idx[r +  8]; const int i3 = sh_idx[r + 12];
        const int i4 = sh_idx[r + 16]; const int i5 = sh_idx[r + 20];
        const int i6 = sh_idx[r + 24]; const int i7 = sh_idx[r + 28];
        const f32x4 a0 = ld4(z + (size_t)i0 * kD + lane * 4);
        const f32x4 a1 = ld4(z + (size_t)i1 * kD + lane * 4);
        const f32x4 a2 = ld4(z + (size_t)i2 * kD + lane * 4);
        const f32x4 a3 = ld4(z + (size_t)i3 * kD + lane * 4);
        const f32x4 a4 = ld4(z + (size_t)i4 * kD + lane * 4);
        const f32x4 a5 = ld4(z + (size_t)i5 * kD + lane * 4);
        const f32x4 a6 = ld4(z + (size_t)i6 * kD + lane * 4);
        const f32x4 a7 = ld4(z + (size_t)i7 * kD + lane * 4);
        acc0 += a0 + a1; acc1 += a2 + a3;
        acc0 += a4 + a5; acc1 += a6 + a7;
    }
    for (; r < m; r += 4) acc0 += ld4(z + (size_t)sh_idx[r] * kD + lane * 4);
    acc0 += acc1;

    ((f32x4*)&sh_part[wave][lane * 4])[0] = acc0;
    __syncthreads();

    const int d = tid;
    float sum = sh_part[0][d] + sh_part[1][d] + sh_part[2][d] + sh_part[3][d];
    const int novf = ovf[0];
    if (novf > 0) {
        for (int j = 0; j < novf; ++j)
            if (ovf[1 + 2 * j] == c) sum += z[(size_t)ovf[2 + 2 * j] * kD + d];
    }

    const float mean   = sum / fmaxf((float)cntc, 1.0f);
    const float nrm    = sqrtf(block_sum256(mean * mean));
    const float mean_n = mean / fmaxf(nrm, kEps);
    const float p    = protos[c * kD + d];
    const float e    = kMom * p + (1.0f - kMom) * mean_n;
    const float nrm2 = sqrtf(block_sum256(e * e));
    const float ema  = e / fmaxf(nrm2, kEps);
    const float cand = (initialized[c] != 0) ? ema : mean_n;
    __builtin_nontemporal_store((cntc > 0) ? cand : p, &out[c * kD + d]);
}

extern "C" void kernel_launch(void* const* d_in, const int* in_sizes, int n_in,
                              void* d_out, int out_size, void* d_ws, size_t ws_size,
                              hipStream_t stream) {
    const float* z           = (const float*)d_in[0];
    const float* protos      = (const float*)d_in[1];
    const int*   initialized = (const int*)d_in[2];
    const int*   labels      = (const int*)d_in[3];
    const int n = in_sizes[3];          // N (labels count)
    float* out = (float*)d_out;

    const int B = (n + kStripe - 1) / kStripe;   // 256 at N=131072
    const size_t cnt_bytes = (((size_t)B * kC * sizeof(unsigned short)) + 255)
                             & ~(size_t)255;
    const size_t need2 = cnt_bytes
                       + (size_t)B * kC * kStripe * sizeof(unsigned short);

    if (B <= 256 && ws_size >= need2) {
        unsigned short* cntmat = (unsigned short*)d_ws;
        unsigned short* idx16  = (unsigned short*)((char*)d_ws + cnt_bytes);
        k_scatter2<<<B, 256, 0, stream>>>(labels, n, cntmat, idx16);
        k_reduce2 <<<kC, 256, 0, stream>>>(z, protos, initialized, cntmat, B,
                                           idx16, out);
        return;
    }

    // fallback: round-10 padded-atomic pipeline
    int* ws  = (int*)d_ws;
    int* cnt = ws;                               // [1024*kCntS]
    int* ovf = ws + 1024 * kCntS;                // [8 + 2N]
    int* idx = ws + 1024 * kCntS + 8 + 2 * n;    // [kC*kCap]
    (void)hipMemsetAsync(ws, 0, (size_t)(1024 * kCntS + 8) * sizeof(int), stream);
    const int threads = (n + 3) / 4;
    const int blocks = (threads + 255) / 256;
    k_scatter<<<blocks, 256, 0, stream>>>(labels, n, cnt, idx, ovf);
    k_reduce <<<kC, 256, 0, stream>>>(z, protos, initialized, cnt, idx, ovf, out);
}